// Round 7
// baseline (106.948 us; speedup 1.0000x reference)
//
#include <hip/hip_runtime.h>

// YOLO loss: out,label [32768,17,7,7] f32 -> scalar f32.
// One BATCH per WAVE, lane = cell (lanes 49..63 clamp, contribution zeroed).
// 34 constant-offset coalesced dword loads per batch; mask = channel-0 label
// register itself. m is exactly 0/1:
//   contrib = d0^2*(0.5+0.5m) + m*(5*(loc+siz)+cls)
//   siz uses (sqrt l - sqrt o)^2 = l+o-2*sqrt(l*o)  (one v_sqrt_f32).
// Single kernel: last block (device fence + ws counter) sums the per-block
// partials in fixed index order -> bitwise deterministic.
// Sum / (32768*49).

#define CELLS  49
#define BPC    833            // 17*49
#define NBATCH 32768
#define NBLK   2040           // partials 8160 B + ctr 4 B = 8164 <= 8 KB ws

__global__ __launch_bounds__(256) void yolo_loss(const float* __restrict__ outp,
                                                 const float* __restrict__ lab,
                                                 float* __restrict__ partial,
                                                 unsigned* __restrict__ ctr,
                                                 float* __restrict__ res) {
    const int lane   = threadIdx.x & 63;
    const int wid    = threadIdx.x >> 6;
    const int gwave  = (blockIdx.x * 256 + threadIdx.x) >> 6;   // global wave id
    const int nwaves = (NBLK * 256) >> 6;                       // 8160
    const int cell   = (lane < CELLS) ? lane : (CELLS - 1);
    const bool valid = (lane < CELLS);

    float acc = 0.0f;
    for (int b = gwave; b < NBATCH; b += nwaves) {
        const float* __restrict__ lb = lab  + b * BPC + cell;
        const float* __restrict__ ob = outp + b * BPC + cell;

        float l[17], o[17];
#pragma unroll
        for (int c = 0; c < 17; ++c) {      // constant offsets -> offset: imm
            l[c] = lb[c * CELLS];
            o[c] = ob[c * CELLS];
        }

        const float m  = l[0];              // objectness label == mask (0 or 1)
        const float d0 = m - o[0];

        float loc = 0.0f, cls = 0.0f, siz = 0.0f;
#pragma unroll
        for (int c = 1; c <= 2; ++c) { const float d = l[c] - o[c]; loc = fmaf(d, d, loc); }
#pragma unroll
        for (int c = 3; c <= 4; ++c) {      // (sqrt l - sqrt o)^2
            const float t = l[c] + o[c];
            const float s = __builtin_amdgcn_sqrtf(l[c] * o[c]);
            siz += fmaf(-2.0f, s, t);
        }
#pragma unroll
        for (int c = 5; c < 17; ++c) { const float d = l[c] - o[c]; cls = fmaf(d, d, cls); }

        const float contrib = d0 * d0 * fmaf(0.5f, m, 0.5f)
                            + m * fmaf(5.0f, loc + siz, cls);
        acc += valid ? contrib : 0.0f;
    }

    // wave64 shuffle reduce
#pragma unroll
    for (int off = 32; off > 0; off >>= 1)
        acc += __shfl_down(acc, off, 64);

    __shared__ float wsum[4];
    __shared__ int isLast;
    if (lane == 0) wsum[wid] = acc;
    __syncthreads();

    if (threadIdx.x == 0) {
        partial[blockIdx.x] = wsum[0] + wsum[1] + wsum[2] + wsum[3];
        __threadfence();                                   // publish partial
        isLast = (atomicAdd(ctr, 1u) == (unsigned)(gridDim.x - 1));
    }
    __syncthreads();

    if (isLast) {
        __threadfence();                                   // acquire all partials
        float s = 0.0f;
        for (int i = threadIdx.x; i < NBLK; i += 256)      // fixed order
            s += partial[i];
#pragma unroll
        for (int off = 32; off > 0; off >>= 1)
            s += __shfl_down(s, off, 64);
        if (lane == 0) wsum[wid] = s;
        __syncthreads();
        if (threadIdx.x == 0)
            res[0] = (wsum[0] + wsum[1] + wsum[2] + wsum[3]) * (1.0f / 1605632.0f);
    }
}

extern "C" void kernel_launch(void* const* d_in, const int* in_sizes, int n_in,
                              void* d_out, int out_size, void* d_ws, size_t ws_size,
                              hipStream_t stream) {
    const float* outp = (const float*)d_in[0];
    const float* lab  = (const float*)d_in[1];
    float* partial    = (float*)d_ws;                          // NBLK floats
    unsigned* ctr     = (unsigned*)((char*)d_ws + NBLK * sizeof(float));
    float* res        = (float*)d_out;

    hipMemsetAsync(ctr, 0, sizeof(unsigned), stream);          // graph-capturable
    yolo_loss<<<NBLK, 256, 0, stream>>>(outp, lab, partial, ctr, res);
}

// Round 8
// 38.707 us; speedup vs baseline: 2.7631x; 2.7631x over previous
//
#include <hip/hip_runtime.h>

// YOLO loss: out,label [32768,17,7,7] f32 -> scalar f32.
// Layout view: [B, 17 channels, 49 cells]. One BATCH per WAVE, lane = cell
// (lanes 49..63 clamp to cell 48 and zero their contribution). All 34 loads
// per batch are base + c*196 with compile-time c -> coalesced constant-offset
// dword loads, no LDS, no LUT, no per-element index math. A wave's 34 loads
// cover two fully-contiguous 3332 B regions -> zero overfetch. The mask is
// the channel-0 label register itself (exactly 0/1):
//   contrib = d0^2*(0.5+0.5m) + m*(5*(loc+siz)+cls)
//   siz via (sqrt l - sqrt o)^2 = l+o-2*sqrt(l*o)   (one v_sqrt_f32)
// Sum / (32768*49). Two-kernel deterministic reduction — NOTE: do NOT fuse
// with a device-fence last-block tail; __threadfence() per block costs ~3x
// (R4/R7: L2 cache-maintenance serializes all streaming traffic).

#define CELLS  49
#define BPC    833            // 17*49
#define NBATCH 32768
#define NBLK   2048           // 8192 waves -> 4 batches per wave

__global__ __launch_bounds__(256) void yolo_partial(const float* __restrict__ outp,
                                                    const float* __restrict__ lab,
                                                    float* __restrict__ partial) {
    const int lane   = threadIdx.x & 63;
    const int gwave  = (blockIdx.x * 256 + threadIdx.x) >> 6;   // global wave id
    const int nwaves = (NBLK * 256) >> 6;                       // 8192
    const int cell   = (lane < CELLS) ? lane : (CELLS - 1);     // clamp lanes 49..63
    const bool valid = (lane < CELLS);

    float acc = 0.0f;
    for (int b = gwave; b < NBATCH; b += nwaves) {
        const float* __restrict__ lb = lab  + b * BPC + cell;
        const float* __restrict__ ob = outp + b * BPC + cell;

        float l[17], o[17];
#pragma unroll
        for (int c = 0; c < 17; ++c) {      // constant offsets -> offset: imm
            l[c] = lb[c * CELLS];
            o[c] = ob[c * CELLS];
        }

        const float m  = l[0];              // objectness label == mask (0 or 1)
        const float d0 = m - o[0];

        float loc = 0.0f, cls = 0.0f, siz = 0.0f;
#pragma unroll
        for (int c = 1; c <= 2; ++c) { const float d = l[c] - o[c]; loc = fmaf(d, d, loc); }
#pragma unroll
        for (int c = 3; c <= 4; ++c) {      // (sqrt l - sqrt o)^2 = l+o-2*sqrt(l*o)
            const float t = l[c] + o[c];
            const float s = __builtin_amdgcn_sqrtf(l[c] * o[c]);
            siz += fmaf(-2.0f, s, t);
        }
#pragma unroll
        for (int c = 5; c < 17; ++c) { const float d = l[c] - o[c]; cls = fmaf(d, d, cls); }

        const float contrib = d0 * d0 * fmaf(0.5f, m, 0.5f)
                            + m * fmaf(5.0f, loc + siz, cls);
        acc += valid ? contrib : 0.0f;
    }

    // wave64 shuffle reduce
#pragma unroll
    for (int off = 32; off > 0; off >>= 1)
        acc += __shfl_down(acc, off, 64);

    __shared__ float wsum[4];
    const int wid = threadIdx.x >> 6;
    if (lane == 0) wsum[wid] = acc;
    __syncthreads();
    if (threadIdx.x == 0)
        partial[blockIdx.x] = wsum[0] + wsum[1] + wsum[2] + wsum[3];
}

__global__ __launch_bounds__(256) void yolo_final(const float* __restrict__ partial,
                                                  float* __restrict__ outv) {
    float acc = 0.0f;
    for (int i = threadIdx.x; i < NBLK; i += 256) acc += partial[i];
#pragma unroll
    for (int off = 32; off > 0; off >>= 1)
        acc += __shfl_down(acc, off, 64);

    __shared__ float wsum[4];
    const int lane = threadIdx.x & 63;
    const int wid  = threadIdx.x >> 6;
    if (lane == 0) wsum[wid] = acc;
    __syncthreads();
    if (threadIdx.x == 0)
        outv[0] = (wsum[0] + wsum[1] + wsum[2] + wsum[3]) * (1.0f / 1605632.0f);
}

extern "C" void kernel_launch(void* const* d_in, const int* in_sizes, int n_in,
                              void* d_out, int out_size, void* d_ws, size_t ws_size,
                              hipStream_t stream) {
    const float* outp = (const float*)d_in[0];
    const float* lab  = (const float*)d_in[1];
    float* partial    = (float*)d_ws;          // NBLK floats (8 KB)
    float* res        = (float*)d_out;

    yolo_partial<<<NBLK, 256, 0, stream>>>(outp, lab, partial);
    yolo_final<<<1, 256, 0, stream>>>(partial, res);
}